// Round 13
// baseline (501.866 us; speedup 1.0000x reference)
//
#include <hip/hip_runtime.h>
#include <stdint.h>

#define B_ 32
#define S_ 2048
#define D_ 64
// q pre-scale: 1/8 (temperature) * log2(e) so exp2(acc) == exp(S/8)
#define QSCALE 0.18033688011112042f

typedef __attribute__((ext_vector_type(8))) short short8v;
typedef __attribute__((ext_vector_type(4))) short short4v;
typedef __attribute__((ext_vector_type(4))) float f32x4;
typedef __attribute__((ext_vector_type(4))) float float4v;
typedef __attribute__((ext_vector_type(4))) int int4v;

static __device__ inline short f2bf(float f){
  uint32_t u = __builtin_bit_cast(uint32_t, f);
  uint32_t r = (u + 0x7fffu + ((u >> 16) & 1u)) >> 16;
  return (short)(uint16_t)r;
}

static __device__ inline void gl16(const void* g, void* l){
  __builtin_amdgcn_global_load_lds(
      (const __attribute__((address_space(1))) void*)g,
      (__attribute__((address_space(3))) void*)l, 16, 0, 0);
}

static __device__ inline uint32_t pkbf(float lo, float hi){
  uint32_t w;
  asm("v_cvt_pk_bf16_f32 %0, %1, %2" : "=v"(w) : "v"(lo), "v"(hi));
  return w;
}

// ---- kernel 0a: q (pre-scaled by log2e/8) and k -> bf16 row-major ----
__global__ __launch_bounds__(256) void cvt_qk(const float* __restrict__ q,
                                              const float* __restrict__ k,
                                              short* __restrict__ qb,
                                              short* __restrict__ kb){
  size_t i = ((size_t)blockIdx.x * 256 + threadIdx.x) * 4;
  float4v a = *(const float4v*)(q + i);
  float4v c = *(const float4v*)(k + i);
  short4v qa = { f2bf(a[0]*QSCALE), f2bf(a[1]*QSCALE), f2bf(a[2]*QSCALE), f2bf(a[3]*QSCALE) };
  short4v kc = { f2bf(c[0]), f2bf(c[1]), f2bf(c[2]), f2bf(c[3]) };
  *(short4v*)(qb + i) = qa;
  *(short4v*)(kb + i) = kc;
}

// ---- kernel 0b: v -> bf16 transposed per batch: vbT[b][d][s] ----
__global__ __launch_bounds__(256) void cvt_v(const float* __restrict__ v,
                                             short* __restrict__ vbT){
  __shared__ float tile[64][65];
  int b = blockIdx.y, st = blockIdx.x;
  int tid = threadIdx.x;
#pragma unroll
  for (int i = 0; i < 4; i++){
    int s = tid + i*256;
    int row = s >> 4, c4 = (s & 15) * 4;
    float4v t = *(const float4v*)(v + ((size_t)b*S_ + st*64 + row)*D_ + c4);
    tile[row][c4+0] = t[0]; tile[row][c4+1] = t[1];
    tile[row][c4+2] = t[2]; tile[row][c4+3] = t[3];
  }
  __syncthreads();
#pragma unroll
  for (int i = 0; i < 2; i++){
    int s = tid + i*256;
    int d = s >> 3, s8 = (s & 7) * 8;
    short8v o;
#pragma unroll
    for (int j = 0; j < 8; j++) o[j] = f2bf(tile[s8 + j][d]);
    *(short8v*)(vbT + ((size_t)b*D_ + d)*S_ + st*64 + s8) = o;
  }
}

// ---- main fused kernel: 16 waves/CU, batch-major co-residency ----
// 256 thr (4 waves), 16 q/wave = 64 q/block, grid (b=32, qt=32):
// co-resident blocks (stride 256 ≡ 0 mod 32) share one batch -> shared K/V
// in L2, single-batch write stream per CU group. 40KB LDS => 4 blocks/CU.
// LDS: K dbuf 2x8K @0 | V dbuf 2x8K @16384 | P 4x2K @32768  (40960 B)
#define WAITN(n) asm volatile("s_waitcnt vmcnt(" #n ")" ::: "memory")
#define BAR   __builtin_amdgcn_s_barrier()

__global__ __launch_bounds__(256, 4) void attn_fused(
    const short* __restrict__ qb, const short* __restrict__ kb,
    const short* __restrict__ vbT, const int* __restrict__ mask,
    float* __restrict__ outp, float* __restrict__ attn)
{
  __shared__ __align__(16) char lds[40960];
  const int tid  = threadIdx.x;
  const int w    = tid >> 6;
  const int lane = tid & 63;
  const int lq   = lane & 15;
  const int g    = lane >> 4;
  const int woff = w << 10;          // per-wave 1KB slice of each DMA issue

  const int b   = blockIdx.x;        // batch-major: co-resident blocks share b
  const int q0b = blockIdx.y * 64;
  const int q0  = q0b + w*16;

  const short* kbb = kb  + (size_t)b*S_*D_;
  const short* vbb = vbT + (size_t)b*D_*S_;

  // K/V DMA source (2 issues x 256 thr x 16B = 8KB tile; src pre-swizzled)
  const int s0 = tid, s1 = 256 + tid;
  const int kr0 = s0 >> 3, kc0 = ((s0 & 7) ^ (kr0 & 7)) << 3;  // shorts
  const int kr1 = s1 >> 3, kc1 = ((s1 & 7) ^ (kr1 & 7)) << 3;
  const short* kSrc0 = kbb + (size_t)kr0*D_ + kc0;   // + ks*D_ per stage
  const short* kSrc1 = kbb + (size_t)kr1*D_ + kc1;
  const short* vSrc0 = vbb + (size_t)kr0*S_ + kc0;   // + ks per stage
  const short* vSrc1 = vbb + (size_t)kr1*S_ + kc1;

  // Q B-fragments (q pre-scaled by log2e/8)
  const size_t qoff = ((size_t)b*S_ + q0 + lq) * D_;
  const short8v qf0 = *(const short8v*)(qb + qoff + g*8);
  const short8v qf1 = *(const short8v*)(qb + qoff + 32 + g*8);

  const int* mrow = mask + ((size_t)b*S_ + q0 + lq) * S_;
  float* aRow = attn + ((size_t)b*S_ + q0 + lq) * S_;

  char* sP = lds + 32768 + (w << 11);       // wave-private 16 rows x 128B

  auto ISSK = [&](int s){ const size_t ks = (size_t)(s << 6); const int o = (s & 1) << 13;
    gl16(kSrc0 + ks*D_, lds + o +    0 + woff);
    gl16(kSrc1 + ks*D_, lds + o + 4096 + woff); };
  auto ISSV = [&](int s){ const size_t ks = (size_t)(s << 6); const int o = (s & 1) << 13;
    gl16(vSrc0 + ks, lds + 16384 + o +    0 + woff);
    gl16(vSrc1 + ks, lds + 16384 + o + 4096 + woff); };

#define LOADM(mv, s) do{ const int _ks = (s) << 6; \
    mv[0] = *(const int4v*)(mrow + _ks +  0 + g*4); \
    mv[1] = *(const int4v*)(mrow + _ks + 16 + g*4); \
    mv[2] = *(const int4v*)(mrow + _ks + 32 + g*4); \
    mv[3] = *(const int4v*)(mrow + _ks + 48 + g*4); }while(0)

  float lrun = 0.f;
  uint32_t bits32[16];               // packed mask bits, 2 stages per entry

  // ========== sweep 1: row sum of exp (max-free), pack mask bits ==========
  int4v mA[4], mB[4];
  ISSK(0); LOADM(mA, 0); LOADM(mB, 1);
  WAITN(8); BAR;                     // queue [K0(2) mA(4) mB(4)] -> drains K0
  {
    // st = 0 (uses mA)
    const char* sKc = lds;
    uint32_t bits = 0;
#pragma unroll
    for (int kkk = 0; kkk < 4; kkk++){
      const int r = (kkk<<4) + lq;
      short8v ka0 = *(const short8v*)(sKc + r*128 + (( g*16     ) ^ ((r & 7) << 4)));
      short8v ka1 = *(const short8v*)(sKc + r*128 + ((64 + g*16 ) ^ ((r & 7) << 4)));
      f32x4 acc = {0.f,0.f,0.f,0.f};
      acc = __builtin_amdgcn_mfma_f32_16x16x32_bf16(ka0, qf0, acc, 0,0,0);
      acc = __builtin_amdgcn_mfma_f32_16x16x32_bf16(ka1, qf1, acc, 0,0,0);
      int4v mu = mA[kkk];
      uint32_t nib = (mu[0]?1u:0u)|(mu[1]?2u:0u)|(mu[2]?4u:0u)|(mu[3]?8u:0u);
      bits |= nib << (kkk*4);
      float e0 = (nib & 1u) ? 0.f : exp2f(acc[0]);
      float e1 = (nib & 2u) ? 0.f : exp2f(acc[1]);
      float e2 = (nib & 4u) ? 0.f : exp2f(acc[2]);
      float e3 = (nib & 8u) ? 0.f : exp2f(acc[3]);
      lrun += (e0 + e1) + (e2 + e3);
    }
    bits32[0] = bits;
  }
  ISSK(1); LOADM(mA, 2);
#pragma unroll
  for (int st = 1; st < 32; ++st){
    if (st == 31) { WAITN(0); } else { WAITN(4); }   // drains K(st) in-order
    BAR;
    if (st < 31) ISSK(st+1);
    const char* sKc = lds + ((st & 1) << 13);
    uint32_t bits = 0;
#pragma unroll
    for (int kkk = 0; kkk < 4; kkk++){
      const int r = (kkk<<4) + lq;
      short8v ka0 = *(const short8v*)(sKc + r*128 + (( g*16     ) ^ ((r & 7) << 4)));
      short8v ka1 = *(const short8v*)(sKc + r*128 + ((64 + g*16 ) ^ ((r & 7) << 4)));
      f32x4 acc = {0.f,0.f,0.f,0.f};
      acc = __builtin_amdgcn_mfma_f32_16x16x32_bf16(ka0, qf0, acc, 0,0,0);
      acc = __builtin_amdgcn_mfma_f32_16x16x32_bf16(ka1, qf1, acc, 0,0,0);
      int4v mu = (st & 1) ? mB[kkk] : mA[kkk];
      uint32_t nib = (mu[0]?1u:0u)|(mu[1]?2u:0u)|(mu[2]?4u:0u)|(mu[3]?8u:0u);
      bits |= nib << (kkk*4);
      float e0 = (nib & 1u) ? 0.f : exp2f(acc[0]);
      float e1 = (nib & 2u) ? 0.f : exp2f(acc[1]);
      float e2 = (nib & 4u) ? 0.f : exp2f(acc[2]);
      float e3 = (nib & 8u) ? 0.f : exp2f(acc[3]);
      lrun += (e0 + e1) + (e2 + e3);
    }
    if (st & 1) bits32[st>>1] |= bits << 16; else bits32[st>>1] = bits;
    if (st + 2 < 32){
      if (st & 1) { LOADM(mB, st+2); } else { LOADM(mA, st+2); }
    }
  }

  lrun += __shfl_xor(lrun, 16, 64);
  lrun += __shfl_xor(lrun, 32, 64);
  const float invl = 1.0f / lrun;

  // ========== sweep 2: recompute, write attn, accumulate PV ==========
  f32x4 oacc[4];
#pragma unroll
  for (int n = 0; n < 4; n++) oacc[n] = (f32x4){0.f,0.f,0.f,0.f};

  auto compute2 = [&](int st){
    const int ks = st << 6;
    const char* sKc = lds + ((st & 1) << 13);
    const char* sVc = lds + 16384 + ((st & 1) << 13);
    const uint32_t bt = (bits32[st>>1] >> ((st & 1) * 16)) & 0xffffu;
#pragma unroll
    for (int c = 0; c < 2; c++){
#pragma unroll
      for (int t2 = 0; t2 < 2; t2++){
        const int kkk = c*2 + t2;
        const int r = (kkk<<4) + lq;
        short8v ka0 = *(const short8v*)(sKc + r*128 + (( g*16     ) ^ ((r & 7) << 4)));
        short8v ka1 = *(const short8v*)(sKc + r*128 + ((64 + g*16 ) ^ ((r & 7) << 4)));
        f32x4 acc = {0.f,0.f,0.f,0.f};
        acc = __builtin_amdgcn_mfma_f32_16x16x32_bf16(ka0, qf0, acc, 0,0,0);
        acc = __builtin_amdgcn_mfma_f32_16x16x32_bf16(ka1, qf1, acc, 0,0,0);
        uint32_t m4 = (bt >> (kkk*4)) & 15u;
        float p0 = (m4 & 1u) ? 0.f : exp2f(acc[0]) * invl;
        float p1 = (m4 & 2u) ? 0.f : exp2f(acc[1]) * invl;
        float p2 = (m4 & 4u) ? 0.f : exp2f(acc[2]) * invl;
        float p3 = (m4 & 8u) ? 0.f : exp2f(acc[3]) * invl;
        f32x4 stv = { p0, p1, p2, p3 };
        *(f32x4*)(aRow + ks + kkk*16 + g*4) = stv;
        uint32_t w0 = pkbf(p0, p1), w1 = pkbf(p2, p3);
        *(uint32_t*)(sP + lq*128 + (((t2*32 + g*8    ) ^ ((lq & 7) << 4))) ) = w0;
        *(uint32_t*)(sP + lq*128 + (((t2*32 + g*8 + 4) ^ ((lq & 7) << 4))) ) = w1;
      }
      short8v pf = *(const short8v*)(sP + lq*128 + ((g*16) ^ ((lq & 7) << 4)));
#pragma unroll
      for (int n = 0; n < 4; n++){
        const int dr = lq + 16*n;
        short8v vf = *(const short8v*)(sVc + dr*128 + ((c*64 + g*16) ^ ((dr & 7) << 4)));
        oacc[n] = __builtin_amdgcn_mfma_f32_16x16x32_bf16(pf, vf, oacc[n], 0,0,0);
      }
    }
  };

  ISSK(0); ISSV(0);
  WAITN(0); BAR;                     // KV0 landed (nothing else outstanding)
  ISSK(1); ISSV(1);
  compute2(0);
#pragma unroll
  for (int st = 1; st < 32; ++st){
    WAITN(4);                        // drains KV(st); stores(st-1) in flight
    BAR;
    if (st < 31){ ISSK(st+1); ISSV(st+1); }
    compute2(st);
  }

  // epilogue: O[q = q0 + 4g + reg][d = lq + 16n]
#pragma unroll
  for (int n = 0; n < 4; n++){
#pragma unroll
    for (int r2 = 0; r2 < 4; r2++){
      outp[((size_t)b*S_ + q0 + 4*g + r2)*D_ + lq + 16*n] = oacc[n][r2];
    }
  }
#undef LOADM
}

extern "C" void kernel_launch(void* const* d_in, const int* in_sizes, int n_in,
                              void* d_out, int out_size, void* d_ws, size_t ws_size,
                              hipStream_t stream) {
  (void)in_sizes; (void)n_in; (void)out_size; (void)ws_size;
  const float* q    = (const float*)d_in[0];
  const float* k    = (const float*)d_in[1];
  const float* v    = (const float*)d_in[2];
  const int*   mask = (const int*)d_in[3];   // bool -> int32 per harness convention

  float* outp = (float*)d_out;
  float* attn = outp + (size_t)B_*S_*D_;     // outputs concatenated: output, attn

  short* qbuf = (short*)d_ws;                // 3 x 8.39MB bf16 scratch
  short* kbuf = qbuf + (size_t)B_*S_*D_;
  short* vbT  = kbuf + (size_t)B_*S_*D_;

  cvt_qk<<<4096, 256, 0, stream>>>(q, k, qbuf, kbuf);
  cvt_v<<<dim3(32, 32), 256, 0, stream>>>(v, vbT);
  attn_fused<<<dim3(32, 32), 256, 0, stream>>>(qbuf, kbuf, vbT, mask, outp, attn);
}

// Round 15
// 373.111 us; speedup vs baseline: 1.3451x; 1.3451x over previous
//
#include <hip/hip_runtime.h>
#include <stdint.h>

#define B_ 32
#define S_ 2048
#define D_ 64
// q pre-scale: 1/8 (temperature) * log2(e) so exp2(acc) == exp(S/8)
#define QSCALE 0.18033688011112042f

typedef __attribute__((ext_vector_type(8))) short short8v;
typedef __attribute__((ext_vector_type(4))) short short4v;
typedef __attribute__((ext_vector_type(4))) float f32x4;
typedef __attribute__((ext_vector_type(4))) float float4v;
typedef __attribute__((ext_vector_type(4))) int int4v;

static __device__ inline short f2bf(float f){
  uint32_t u = __builtin_bit_cast(uint32_t, f);
  uint32_t r = (u + 0x7fffu + ((u >> 16) & 1u)) >> 16;
  return (short)(uint16_t)r;
}

static __device__ inline void gl16(const void* g, void* l){
  __builtin_amdgcn_global_load_lds(
      (const __attribute__((address_space(1))) void*)g,
      (__attribute__((address_space(3))) void*)l, 16, 0, 0);
}

static __device__ inline uint32_t pkbf(float lo, float hi){
  uint32_t w;
  asm("v_cvt_pk_bf16_f32 %0, %1, %2" : "=v"(w) : "v"(lo), "v"(hi));
  return w;
}

// ---- kernel 0a: q (pre-scaled by log2e/8) and k -> bf16 row-major ----
__global__ __launch_bounds__(256) void cvt_qk(const float* __restrict__ q,
                                              const float* __restrict__ k,
                                              short* __restrict__ qb,
                                              short* __restrict__ kb){
  size_t i = ((size_t)blockIdx.x * 256 + threadIdx.x) * 4;
  float4v a = *(const float4v*)(q + i);
  float4v c = *(const float4v*)(k + i);
  short4v qa = { f2bf(a[0]*QSCALE), f2bf(a[1]*QSCALE), f2bf(a[2]*QSCALE), f2bf(a[3]*QSCALE) };
  short4v kc = { f2bf(c[0]), f2bf(c[1]), f2bf(c[2]), f2bf(c[3]) };
  *(short4v*)(qb + i) = qa;
  *(short4v*)(kb + i) = kc;
}

// ---- kernel 0b: v -> bf16 transposed per batch: vbT[b][d][s] ----
__global__ __launch_bounds__(256) void cvt_v(const float* __restrict__ v,
                                             short* __restrict__ vbT){
  __shared__ float tile[64][65];
  int b = blockIdx.y, st = blockIdx.x;
  int tid = threadIdx.x;
#pragma unroll
  for (int i = 0; i < 4; i++){
    int s = tid + i*256;
    int row = s >> 4, c4 = (s & 15) * 4;
    float4v t = *(const float4v*)(v + ((size_t)b*S_ + st*64 + row)*D_ + c4);
    tile[row][c4+0] = t[0]; tile[row][c4+1] = t[1];
    tile[row][c4+2] = t[2]; tile[row][c4+3] = t[3];
  }
  __syncthreads();
#pragma unroll
  for (int i = 0; i < 2; i++){
    int s = tid + i*256;
    int d = s >> 3, s8 = (s & 7) * 8;
    short8v o;
#pragma unroll
    for (int j = 0; j < 8; j++) o[j] = f2bf(tile[s8 + j][d]);
    *(short8v*)(vbT + ((size_t)b*D_ + d)*S_ + st*64 + s8) = o;
  }
}

// ---- main fused kernel: TRUE depth-2 pipeline, triple-buffered K/V ----
// 256 thr (4 waves), 64 q/block, grid (qt=32, b=32), 56KB LDS, 2 blk/CU.
// Queue traces (per wave, in-order vmcnt):
//  sweep1 steady @st: [K(st):2, m(st):4, K(st+1):2, m(st+1):4] -> WAITN(10)
//    drains exactly K(st); compiler's reg-dep wait (<=6) covers m(st).
//  sweep2 steady @st: [KV(st):4, stores(st-2):4, KV(st+1):4, stores(st-1):4]
//    -> WAITN(12) drains exactly KV(st); stores never force-drained.
// LDS: K 3x8K @0 | V 3x8K @24576 | P 4x2K @49152  (57344 B)
#define WAITN(n) asm volatile("s_waitcnt vmcnt(" #n ")" ::: "memory")
#define BAR   __builtin_amdgcn_s_barrier()

__global__ __launch_bounds__(256, 2) void attn_fused(
    const short* __restrict__ qb, const short* __restrict__ kb,
    const short* __restrict__ vbT, const int* __restrict__ mask,
    float* __restrict__ outp, float* __restrict__ attn)
{
  __shared__ __align__(16) char lds[57344];
  const int tid  = threadIdx.x;
  const int w    = tid >> 6;
  const int lane = tid & 63;
  const int lq   = lane & 15;
  const int g    = lane >> 4;
  const int woff = w << 10;          // per-wave 1KB slice of each DMA issue

  const int b   = blockIdx.y;
  const int q0b = blockIdx.x * 64;
  const int q0  = q0b + w*16;

  const short* kbb = kb  + (size_t)b*S_*D_;
  const short* vbb = vbT + (size_t)b*D_*S_;

  // K/V DMA source (2 issues x 256 thr x 16B = 8KB tile; src pre-swizzled)
  const int s0 = tid, s1 = 256 + tid;
  const int kr0 = s0 >> 3, kc0 = ((s0 & 7) ^ (kr0 & 7)) << 3;  // shorts
  const int kr1 = s1 >> 3, kc1 = ((s1 & 7) ^ (kr1 & 7)) << 3;
  const short* kSrc0 = kbb + (size_t)kr0*D_ + kc0;   // + ks*D_ per stage
  const short* kSrc1 = kbb + (size_t)kr1*D_ + kc1;
  const short* vSrc0 = vbb + (size_t)kr0*S_ + kc0;   // + ks per stage
  const short* vSrc1 = vbb + (size_t)kr1*S_ + kc1;

  // Q B-fragments (q pre-scaled by log2e/8)
  const size_t qoff = ((size_t)b*S_ + q0 + lq) * D_;
  const short8v qf0 = *(const short8v*)(qb + qoff + g*8);
  const short8v qf1 = *(const short8v*)(qb + qoff + 32 + g*8);

  const int* mrow = mask + ((size_t)b*S_ + q0 + lq) * S_;
  float* aRow = attn + ((size_t)b*S_ + q0 + lq) * S_;

  char* sP = lds + 49152 + (w << 11);       // wave-private 16 rows x 128B

  auto ISSK = [&](int s){ const size_t ks = (size_t)(s << 6); const int o = (s % 3) << 13;
    gl16(kSrc0 + ks*D_, lds + o +    0 + woff);
    gl16(kSrc1 + ks*D_, lds + o + 4096 + woff); };
  auto ISSV = [&](int s){ const size_t ks = (size_t)(s << 6); const int o = (s % 3) << 13;
    gl16(vSrc0 + ks, lds + 24576 + o +    0 + woff);
    gl16(vSrc1 + ks, lds + 24576 + o + 4096 + woff); };

#define LOADM(mv, s) do{ const int _ks = (s) << 6; \
    mv[0] = *(const int4v*)(mrow + _ks +  0 + g*4); \
    mv[1] = *(const int4v*)(mrow + _ks + 16 + g*4); \
    mv[2] = *(const int4v*)(mrow + _ks + 32 + g*4); \
    mv[3] = *(const int4v*)(mrow + _ks + 48 + g*4); }while(0)

  float lrun = 0.f;
  uint32_t bits32[16];               // packed mask bits, 2 stages per entry

#define SWEEP1_BODY(st, mv) do{ \
    const char* sKc = lds + (((st) % 3) << 13); \
    uint32_t bits = 0; \
    _Pragma("unroll") \
    for (int kkk = 0; kkk < 4; kkk++){ \
      const int r = (kkk<<4) + lq; \
      short8v ka0 = *(const short8v*)(sKc + r*128 + (( g*16     ) ^ ((r & 7) << 4))); \
      short8v ka1 = *(const short8v*)(sKc + r*128 + ((64 + g*16 ) ^ ((r & 7) << 4))); \
      f32x4 acc = {0.f,0.f,0.f,0.f}; \
      acc = __builtin_amdgcn_mfma_f32_16x16x32_bf16(ka0, qf0, acc, 0,0,0); \
      acc = __builtin_amdgcn_mfma_f32_16x16x32_bf16(ka1, qf1, acc, 0,0,0); \
      int4v mu = mv[kkk]; \
      uint32_t nib = (mu[0]?1u:0u)|(mu[1]?2u:0u)|(mu[2]?4u:0u)|(mu[3]?8u:0u); \
      bits |= nib << (kkk*4); \
      float e0 = (nib & 1u) ? 0.f : exp2f(acc[0]); \
      float e1 = (nib & 2u) ? 0.f : exp2f(acc[1]); \
      float e2 = (nib & 4u) ? 0.f : exp2f(acc[2]); \
      float e3 = (nib & 8u) ? 0.f : exp2f(acc[3]); \
      lrun += (e0 + e1) + (e2 + e3); \
    } \
    if ((st) & 1) bits32[(st)>>1] |= bits << 16; else bits32[(st)>>1] = bits; \
  }while(0)

  // ========== sweep 1: depth-2 (K 2 stages ahead, mask 2 stages ahead) =====
  int4v mA[4], mB[4];
  ISSK(0); ISSK(1); LOADM(mA, 0); LOADM(mB, 1);
  // st=0: queue [K0:2 K1:2 mA:4 mB:4]=12 -> WAITN(10) drains K0
  WAITN(10); BAR; ISSK(2); SWEEP1_BODY(0, mA); LOADM(mA, 2);
#pragma unroll
  for (int st = 1; st < 32; ++st){
    if (st == 31) { WAITN(4); } else { WAITN(10); }
    BAR;
    if (st + 2 < 32) ISSK(st+2);
    if (st & 1) { SWEEP1_BODY(st, mB); } else { SWEEP1_BODY(st, mA); }
    if (st + 2 < 32){
      if (st & 1) { LOADM(mB, st+2); } else { LOADM(mA, st+2); }
    }
  }

  lrun += __shfl_xor(lrun, 16, 64);
  lrun += __shfl_xor(lrun, 32, 64);
  const float invl = 1.0f / lrun;

  // ========== sweep 2: depth-2 K/V, stores never force-drained ==========
  f32x4 oacc[4];
#pragma unroll
  for (int n = 0; n < 4; n++) oacc[n] = (f32x4){0.f,0.f,0.f,0.f};

  auto compute2 = [&](int st){
    const int ks = st << 6;
    const char* sKc = lds + ((st % 3) << 13);
    const char* sVc = lds + 24576 + ((st % 3) << 13);
    const uint32_t bt = (bits32[st>>1] >> ((st & 1) * 16)) & 0xffffu;
#pragma unroll
    for (int c = 0; c < 2; c++){
#pragma unroll
      for (int t2 = 0; t2 < 2; t2++){
        const int kkk = c*2 + t2;
        const int r = (kkk<<4) + lq;
        short8v ka0 = *(const short8v*)(sKc + r*128 + (( g*16     ) ^ ((r & 7) << 4)));
        short8v ka1 = *(const short8v*)(sKc + r*128 + ((64 + g*16 ) ^ ((r & 7) << 4)));
        f32x4 acc = {0.f,0.f,0.f,0.f};
        acc = __builtin_amdgcn_mfma_f32_16x16x32_bf16(ka0, qf0, acc, 0,0,0);
        acc = __builtin_amdgcn_mfma_f32_16x16x32_bf16(ka1, qf1, acc, 0,0,0);
        uint32_t m4 = (bt >> (kkk*4)) & 15u;
        float p0 = (m4 & 1u) ? 0.f : exp2f(acc[0]) * invl;
        float p1 = (m4 & 2u) ? 0.f : exp2f(acc[1]) * invl;
        float p2 = (m4 & 4u) ? 0.f : exp2f(acc[2]) * invl;
        float p3 = (m4 & 8u) ? 0.f : exp2f(acc[3]) * invl;
        f32x4 stv = { p0, p1, p2, p3 };
        *(f32x4*)(aRow + ks + kkk*16 + g*4) = stv;
        uint32_t w0 = pkbf(p0, p1), w1 = pkbf(p2, p3);
        *(uint32_t*)(sP + lq*128 + (((t2*32 + g*8    ) ^ ((lq & 7) << 4))) ) = w0;
        *(uint32_t*)(sP + lq*128 + (((t2*32 + g*8 + 4) ^ ((lq & 7) << 4))) ) = w1;
      }
      short8v pf = *(const short8v*)(sP + lq*128 + ((g*16) ^ ((lq & 7) << 4)));
#pragma unroll
      for (int n = 0; n < 4; n++){
        const int dr = lq + 16*n;
        short8v vf = *(const short8v*)(sVc + dr*128 + ((c*64 + g*16) ^ ((dr & 7) << 4)));
        oacc[n] = __builtin_amdgcn_mfma_f32_16x16x32_bf16(pf, vf, oacc[n], 0,0,0);
      }
    }
  };

  ISSK(0); ISSV(0); ISSK(1); ISSV(1);
  // st=0: queue [KV0:4 KV1:4] -> WAITN(4) drains KV0
  WAITN(4); BAR; ISSK(2); ISSV(2); compute2(0);
  // st=1: queue [KV1:4 KV2:4 stores0:4]=12 -> WAITN(8) drains KV1
  WAITN(8); BAR; ISSK(3); ISSV(3); compute2(1);
#pragma unroll
  for (int st = 2; st < 32; ++st){
    // steady queue: [KV(st):4 stores(st-2):4 KV(st+1):4 stores(st-1):4]=16
    if (st == 31) { WAITN(8); } else { WAITN(12); }
    BAR;
    if (st + 2 < 32){ ISSK(st+2); ISSV(st+2); }
    compute2(st);
  }

  // epilogue: O[q = q0 + 4g + reg][d = lq + 16n]
#pragma unroll
  for (int n = 0; n < 4; n++){
#pragma unroll
    for (int r2 = 0; r2 < 4; r2++){
      outp[((size_t)b*S_ + q0 + 4*g + r2)*D_ + lq + 16*n] = oacc[n][r2];
    }
  }
#undef LOADM
#undef SWEEP1_BODY
}

extern "C" void kernel_launch(void* const* d_in, const int* in_sizes, int n_in,
                              void* d_out, int out_size, void* d_ws, size_t ws_size,
                              hipStream_t stream) {
  (void)in_sizes; (void)n_in; (void)out_size; (void)ws_size;
  const float* q    = (const float*)d_in[0];
  const float* k    = (const float*)d_in[1];
  const float* v    = (const float*)d_in[2];
  const int*   mask = (const int*)d_in[3];   // bool -> int32 per harness convention

  float* outp = (float*)d_out;
  float* attn = outp + (size_t)B_*S_*D_;     // outputs concatenated: output, attn

  short* qbuf = (short*)d_ws;                // 3 x 8.39MB bf16 scratch
  short* kbuf = qbuf + (size_t)B_*S_*D_;
  short* vbT  = kbuf + (size_t)B_*S_*D_;

  cvt_qk<<<4096, 256, 0, stream>>>(q, k, qbuf, kbuf);
  cvt_v<<<dim3(32, 32), 256, 0, stream>>>(v, vbT);
  attn_fused<<<dim3(32, 32), 256, 0, stream>>>(qbuf, kbuf, vbT, mask, outp, attn);
}